// Round 2
// baseline (2340.407 us; speedup 1.0000x reference)
//
#include <hip/hip_runtime.h>

#define NROW 5000
#define NPAD 5120   // padded rows
#define KW   80     // u64 words per padded row
#define KC   80     // 64-k chunks
#define KZ   4      // split-K
#define KCQ  20     // chunks per split
#define HDIM 128
#define MTI  5      // 32-row MFMA tiles per block (160 rows); 32 m-blocks * 4 e * 4 kz = 512
#define MROWS (MTI * 32)
#define GRID1 512   // persistent grid: exactly 2 blocks/CU * 256 CU
#define NT2  625    // 8-row gemm2 tiles (625*8 = 5000 exactly)
#define FXS  4194304.0f                  // 2^22 fixed-point scale
#define PART ((size_t)4 * NROW * HDIM)   // agg elements per kz part

typedef _Float16 f16x8 __attribute__((ext_vector_type(8)));
typedef float f32x16 __attribute__((ext_vector_type(16)));

__device__ __forceinline__ unsigned short f2h_int(int v) {   // exact for |v| <= 2048
    union { _Float16 h; unsigned short u; } c;
    c.h = (_Float16)(float)v;
    return c.u;
}
// q = round(h*2^22); digits base 2048: q == d1*2048 + d0
__device__ __forceinline__ void fx_digits(float h, unsigned short& d1, unsigned short& d0) {
    int q = (int)rintf(h * FXS);
    d1 = f2h_int(q >> 11);
    d0 = f2h_int(q & 2047);
}

// Fragment-major B layout: element (kc, pl, kk, half, col, j) holds digit plane pl of
// k = kc*64 + kk*16 + half*8 + j for column col. A wave's f16x8 fragment load is
// contiguous (512 B per half-wave). strides in f16 units: kc 16384, pl 8192, kk 2048,
// half 1024, col 8.
__device__ __forceinline__ size_t bt_idx(int kc, int pl, int kk, int half, int col, int j) {
    return (((((size_t)kc * 2 + pl) * 4 + kk) * 2 + half) * 128 + col) * 8 + j;
}

// ---- grid-wide barrier: device-scope atomic counter, one per barrier slot ----
__device__ __forceinline__ void gridbar(int* bar, int idx) {
    __syncthreads();
    if (threadIdx.x == 0) {
        __hip_atomic_fetch_add(&bar[idx], 1, __ATOMIC_ACQ_REL, __HIP_MEMORY_SCOPE_AGENT);
        while (__hip_atomic_load(&bar[idx], __ATOMIC_ACQUIRE, __HIP_MEMORY_SCOPE_AGENT) < GRID1)
            __builtin_amdgcn_s_sleep(2);
    }
    __syncthreads();
}

// ---- prep: resolve atom indices; detect int32 vs int64 storage device-side; zero barriers ----
__global__ __launch_bounds__(256) void prep_atom_kernel(const unsigned int* __restrict__ atomw,
                                                        int* __restrict__ atomIdx,
                                                        int* __restrict__ bar) {
    if (blockIdx.x == 0 && threadIdx.x < 16) bar[threadIdx.x] = 0;
    __shared__ int s_is64;
    if (threadIdx.x == 0) {
        bool all0 = true, anynz = false;
        for (int j = 0; j < 64; ++j) {
            unsigned lo = atomw[2 * j], hi = atomw[2 * j + 1];
            all0 = all0 && (hi == 0u);
            anynz = anynz || (lo != 0u);
        }
        s_is64 = (all0 && anynz) ? 1 : 0;
    }
    __syncthreads();
    int v = blockIdx.x * 256 + threadIdx.x;
    if (v < NROW) atomIdx[v] = s_is64 ? (int)atomw[2 * v] : (int)atomw[v];
}

// ---- prep: bit-pack adjacency, kc-major: packedT[(e*KC + c)*NPAD + r] ----
__global__ __launch_bounds__(256) void prep_pack_kernel(const int* __restrict__ adjs,
                                                        unsigned long long* __restrict__ packedT) {
    const int er = blockIdx.x;            // [0, 4*NPAD)
    const int e = er / NPAD;
    const int r = er - e * NPAD;
    const int wave = threadIdx.x >> 6;
    const int lane = threadIdx.x & 63;
    const int* rowp = adjs + ((size_t)e * NROW + r) * NROW;
    unsigned long long* outp = packedT + (size_t)e * KC * NPAD + r;
    const bool rok = (r < NROW);
    for (int c = wave; c < KW; c += 4) {
        int u = c * 64 + lane;
        int val = (rok && u < NROW) ? rowp[u] : 0;
        unsigned long long m = __ballot(val == 1);
        if (lane == 0) outp[(size_t)c * NPAD] = m;
    }
}

// ------- prep: h0 -> fragment-major f16 digit planes from fp32 embedding -------
__global__ __launch_bounds__(256) void prep_h0T_kernel(const int* __restrict__ atomIdx,
                                                       const float* __restrict__ emb,
                                                       unsigned short* __restrict__ hTt) {
    const int i = blockIdx.y;
    const int v = blockIdx.x * 256 + threadIdx.x;   // < KPAD (k index)
    float val = 0.f;
    if (v < NROW) val = emb[(size_t)atomIdx[v] * HDIM + i];
    unsigned short d1, d0;
    fx_digits(val, d1, d0);
    const int kc = v >> 6, kk = (v >> 4) & 3, half = (v >> 3) & 1, j = v & 7;
    hTt[bt_idx(kc, 0, kk, half, i, j)] = d1;
    hTt[bt_idx(kc, 1, kk, half, i, j)] = d0;
}

// ---------------- prep: h0 fp32 row-major state ----------------
__global__ __launch_bounds__(256) void prep_h0f_kernel(const int* __restrict__ atomIdx,
                                                       const float* __restrict__ emb,
                                                       float* __restrict__ h) {
    int idx = blockIdx.x * 256 + threadIdx.x;   // < NROW*HDIM
    int v = idx >> 7, i = idx & 127;
    h[idx] = emb[(size_t)atomIdx[v] * HDIM + i];
}

// ---------------- prep: Htr[(e*128+j)*128 + i] = H[e][i][j] (fp32) ----------------
__global__ __launch_bounds__(256) void prep_Ht_kernel(const float* __restrict__ H,
                                                      float* __restrict__ Htr) {
    int idx = blockIdx.x * 256 + threadIdx.x;   // < 4*128*128
    int e = idx >> 14;
    int j = (idx >> 7) & 127;
    int i = idx & 127;
    Htr[idx] = H[((size_t)e * HDIM + i) * HDIM + j];
}

// ---- FUSED t-loop: per t { G1: agg = A*h (MFMA, exact digits); gridbar;
//                            G2: msg = Htr*agg, sigmoid, update h/out/digits; gridbar } ----
// 512 blocks * 256 thr, 2 blocks/CU guaranteed by launch bounds (20.5 KB LDS, <=256 VGPR).
__global__ __launch_bounds__(256, 2) void fused_kernel(const unsigned long long* __restrict__ packedT,
                                                       unsigned short* __restrict__ hTt,
                                                       float* __restrict__ agg,
                                                       const float* __restrict__ Htr,
                                                       float* __restrict__ hf,
                                                       float* __restrict__ out,
                                                       int* __restrict__ bar) {
    __shared__ float aggs[8][512];             // 16 KB
    __shared__ unsigned short hs[2][128][8];   // 4 KB digit transpose buffers
    const int tid = threadIdx.x;
    const int bid = blockIdx.x;

    // ---- G1 geometry: bid -> (m-block, e, kz) ----
    const int mblk = bid & 31;
    const int e1 = (bid >> 5) & 3;
    const int kz = bid >> 7;
    const int lane = tid & 63;
    const int wave = tid >> 6;
    const int l31 = lane & 31;
    const int l1 = lane >> 5;            // half-wave selector
    const int sh2 = l1 * 8;              // bit offset within 16-bit k-group
    const int col = wave * 32 + l31;
    const int m0 = mblk * MROWS;
    const int kc0 = kz * KCQ;

    // ---- G2 geometry: 8-row tiles, thread = (i-pair, row-group) ----
    const int ip = tid & 63;
    const int vg = tid >> 6;             // 0..3, rows vg*2, vg*2+1
    const int i0 = ip * 2;

    for (int t = 0; t < 4; ++t) {
        // ================= G1: agg[kz] = A(e) * h  (exact, LDS-free) =================
        {
            f32x16 acc[2][MTI];          // [pl][mt] = 160 VGPR
#pragma unroll
            for (int pl = 0; pl < 2; ++pl)
#pragma unroll
                for (int mt = 0; mt < MTI; ++mt) acc[pl][mt] = (f32x16)(0.f);

            const unsigned long long* ap = packedT + ((size_t)e1 * KC + kc0) * NPAD + m0 + l31;
            const _Float16* bp = (const _Float16*)hTt + (size_t)kc0 * 16384 +
                                 (size_t)l1 * 1024 + (size_t)col * 8;

            for (int kc = 0; kc < KCQ; ++kc) {
                unsigned long long aw[MTI];
#pragma unroll
                for (int mt = 0; mt < MTI; ++mt) aw[mt] = ap[mt * 32];

                f16x8 bf[2][4];          // [pl][kk]
#pragma unroll
                for (int pl = 0; pl < 2; ++pl)
#pragma unroll
                    for (int kk = 0; kk < 4; ++kk)
                        bf[pl][kk] = *(const f16x8*)(bp + pl * 8192 + kk * 2048);

                ap += NPAD;
                bp += 16384;

#pragma unroll
                for (int kk = 0; kk < 4; ++kk) {
#pragma unroll
                    for (int mt = 0; mt < MTI; ++mt) {
                        unsigned int w = (kk < 2) ? (unsigned int)aw[mt]
                                                  : (unsigned int)(aw[mt] >> 32);
                        unsigned int b = (w >> ((kk & 1) * 16 + sh2)) & 0xFFu;
                        unsigned int y = b | (b << 15);
                        union { unsigned int u[4]; f16x8 h; } A;
#pragma unroll
                        for (int q = 0; q < 4; ++q)
                            A.u[q] = ((y >> (2 * q)) & 0x00010001u) * 0x3C00u;
#pragma unroll
                        for (int pl = 0; pl < 2; ++pl)
                            acc[pl][mt] = __builtin_amdgcn_mfma_f32_32x32x16_f16(
                                A.h, bf[pl][kk], acc[pl][mt], 0, 0, 0);
                    }
                }
            }

            // epilogue: exact digit combine in double, one optimal fp32 rounding
            float* aggz = agg + (size_t)kz * PART;
#pragma unroll
            for (int mt = 0; mt < MTI; ++mt)
#pragma unroll
                for (int reg = 0; reg < 16; ++reg) {
                    int row = (reg & 3) + 8 * (reg >> 2) + 4 * l1;
                    int v = m0 + mt * 32 + row;
                    if (v < NROW) {
                        double d = (double)acc[0][mt][reg] * 2048.0 + (double)acc[1][mt][reg];
                        aggz[((size_t)e1 * NROW + v) * HDIM + col] = (float)(d * (1.0 / 4194304.0));
                    }
                }
        }
        gridbar(bar, 2 * t);

        // ================= G2: per 8-row tile =================
        float* outp = out + (size_t)t * NROW * HDIM;
        for (int tile = bid; tile < NT2; tile += GRID1) {
            const int v0 = tile * 8;
            // stage 8 rows x 512 (sum of 4 kz parts), float4
#pragma unroll
            for (int it = 0; it < 4; ++it) {
                int idx = it * 256 + tid;          // float4 index, 0..1023
                int r = idx >> 7;
                int c = (idx & 127) * 4;
                int e = c >> 7, j = c & 127;
                size_t o = ((size_t)e * NROW + (v0 + r)) * HDIM + j;
                float4 a0 = *(const float4*)&agg[o];
                float4 a1 = *(const float4*)&agg[PART + o];
                float4 a2 = *(const float4*)&agg[2 * PART + o];
                float4 a3 = *(const float4*)&agg[3 * PART + o];
                *(float4*)&aggs[r][c] = make_float4((a0.x + a1.x) + (a2.x + a3.x),
                                                    (a0.y + a1.y) + (a2.y + a3.y),
                                                    (a0.z + a1.z) + (a2.z + a3.z),
                                                    (a0.w + a1.w) + (a2.w + a3.w));
            }
            __syncthreads();

            float m[2][2][4];                       // [row][i-col][k-lane]
#pragma unroll
            for (int r = 0; r < 2; ++r)
#pragma unroll
                for (int q = 0; q < 2; ++q)
#pragma unroll
                    for (int k = 0; k < 4; ++k) m[r][q][k] = 0.f;

            const int rb = vg * 2;
            for (int cg = 0; cg < 128; ++cg) {
                int c = cg * 4;
                float4 q0 = *(const float4*)&aggs[rb][c];       // broadcast, conflict-free
                float4 q1 = *(const float4*)&aggs[rb + 1][c];
                float a0v[4] = {q0.x, q0.y, q0.z, q0.w};
                float a1v[4] = {q1.x, q1.y, q1.z, q1.w};
#pragma unroll
                for (int k = 0; k < 4; ++k) {
                    float2 w = *(const float2*)&Htr[(size_t)(c + k) * HDIM + i0];
                    m[0][0][k] += a0v[k] * w.x;
                    m[0][1][k] += a0v[k] * w.y;
                    m[1][0][k] += a1v[k] * w.x;
                    m[1][1][k] += a1v[k] * w.y;
                }
            }

#pragma unroll
            for (int r = 0; r < 2; ++r) {
                int vr = rb + r;
                int v = v0 + vr;
                size_t o = (size_t)v * HDIM + i0;
                float2 hv = *(const float2*)&hf[o];
                float ms0 = (m[r][0][0] + m[r][0][1]) + (m[r][0][2] + m[r][0][3]);
                float ms1 = (m[r][1][0] + m[r][1][1]) + (m[r][1][2] + m[r][1][3]);
                float x0 = hv.x + ms0;
                float x1 = hv.y + ms1;
                float s0 = 1.0f / (1.0f + expf(-x0));
                float s1 = 1.0f / (1.0f + expf(-x1));
                *(float2*)&outp[o] = make_float2(s0, s1);
                *(float2*)&hf[o] = make_float2(s0, s1);
                unsigned short d1a, d0a, d1b, d0b;
                fx_digits(s0, d1a, d0a);
                fx_digits(s1, d1b, d0b);
                hs[0][i0][vr] = d1a;
                hs[1][i0][vr] = d0a;
                hs[0][i0 + 1][vr] = d1b;
                hs[1][i0 + 1][vr] = d0b;
            }
            __syncthreads();
            if (tid < 128) {    // one uint4 (8 k-entries) per plane, coalesced
                const int kc = v0 >> 6, kk = (v0 >> 4) & 3, half = (v0 >> 3) & 1;
#pragma unroll
                for (int pl = 0; pl < 2; ++pl)
                    *(uint4*)&hTt[bt_idx(kc, pl, kk, half, tid, 0)] =
                        *(const uint4*)&hs[pl][tid][0];
            }
        }
        if (t != 3) gridbar(bar, 2 * t + 1);
    }
}

extern "C" void kernel_launch(void* const* d_in, const int* in_sizes, int n_in,
                              void* d_out, int out_size, void* d_ws, size_t ws_size,
                              hipStream_t stream) {
    const unsigned int* atomw = (const unsigned int*)d_in[0];  // int32 OR int64 — sniffed on device
    const int* adjs = (const int*)d_in[1];                     // int32
    // d_in[2] = max_time_steps; reference constant T=4 hard-coded
    const float* emb = (const float*)d_in[3];                  // fp32
    const float* H = (const float*)d_in[4];                    // fp32
    float* out = (float*)d_out;                                // fp32 output

    char* ws = (char*)d_ws;
    unsigned long long* packedT = (unsigned long long*)ws;           // 13,107,200 B (kc-major)
    size_t off = (size_t)4 * KC * NPAD * 8;
    unsigned short* hTt = (unsigned short*)(ws + off);               // 2 planes fragment-major
    off += (size_t)2 * KC * HDIM * 64 * 2;
    float* hf = (float*)(ws + off);                                  // 2,560,000 B
    off += (size_t)NROW * HDIM * 4;
    float* agg = (float*)(ws + off);                                 // 4 parts = 40,960,000 B
    off += (size_t)KZ * PART * 4;
    float* Htr = (float*)(ws + off);                                 // 262,144 B
    off += (size_t)4 * HDIM * HDIM * 4;
    int* atomIdx = (int*)(ws + off);                                 // 20,000 B
    off += (size_t)NROW * 4;
    off = (off + 63) & ~(size_t)63;
    int* bar = (int*)(ws + off);                                     // 8 barrier slots (64 B)
    off += 64;

    prep_atom_kernel<<<dim3((NROW + 255) / 256), 256, 0, stream>>>(atomw, atomIdx, bar);
    prep_pack_kernel<<<dim3(4 * NPAD), 256, 0, stream>>>(adjs, packedT);
    prep_h0T_kernel<<<dim3(NPAD / 256, HDIM), 256, 0, stream>>>(atomIdx, emb, hTt);
    prep_h0f_kernel<<<dim3(NROW * HDIM / 256), 256, 0, stream>>>(atomIdx, emb, hf);
    prep_Ht_kernel<<<dim3(4 * HDIM * HDIM / 256), 256, 0, stream>>>(H, Htr);

    fused_kernel<<<dim3(GRID1), 256, 0, stream>>>(packedT, hTt, agg, Htr, hf, out, bar);
}

// Round 3
// 1504.014 us; speedup vs baseline: 1.5561x; 1.5561x over previous
//
#include <hip/hip_runtime.h>

#define NROW 5000
#define NPAD 5120   // padded rows
#define KW   80     // u64 words per padded row
#define KC   80     // 64-k chunks
#define KZ   4      // split-K
#define KCQ  20     // chunks per split
#define HDIM 128
#define MTI  4      // 32-row MFMA tiles per block (128 rows); acc = 128 AGPR, no spill
#define MROWS (MTI * 32)
#define FXS  4194304.0f                  // 2^22 fixed-point scale
#define PART ((size_t)4 * NROW * HDIM)   // agg elements per kz part

typedef _Float16 f16x8 __attribute__((ext_vector_type(8)));
typedef float f32x16 __attribute__((ext_vector_type(16)));

__device__ __forceinline__ unsigned short f2h_int(int v) {   // exact for |v| <= 2048
    union { _Float16 h; unsigned short u; } c;
    c.h = (_Float16)(float)v;
    return c.u;
}
// q = round(h*2^22); digits base 2048: q == d1*2048 + d0
__device__ __forceinline__ void fx_digits(float h, unsigned short& d1, unsigned short& d0) {
    int q = (int)rintf(h * FXS);
    d1 = f2h_int(q >> 11);
    d0 = f2h_int(q & 2047);
}

// Fragment-major B layout: element (kc, pl, kk, half, col, j) holds digit plane pl of
// k = kc*64 + kk*16 + half*8 + j for column col. A wave's f16x8 fragment load is
// contiguous (512 B per half-wave). strides in f16 units: kc 16384, pl 8192, kk 2048,
// half 1024, col 8.
__device__ __forceinline__ size_t bt_idx(int kc, int pl, int kk, int half, int col, int j) {
    return (((((size_t)kc * 2 + pl) * 4 + kk) * 2 + half) * 128 + col) * 8 + j;
}

// ---- prep: resolve atom indices; detect int32 vs int64 storage device-side ----
__global__ __launch_bounds__(256) void prep_atom_kernel(const unsigned int* __restrict__ atomw,
                                                        int* __restrict__ atomIdx) {
    __shared__ int s_is64;
    if (threadIdx.x == 0) {
        bool all0 = true, anynz = false;
        for (int j = 0; j < 64; ++j) {
            unsigned lo = atomw[2 * j], hi = atomw[2 * j + 1];
            all0 = all0 && (hi == 0u);
            anynz = anynz || (lo != 0u);
        }
        s_is64 = (all0 && anynz) ? 1 : 0;
    }
    __syncthreads();
    int v = blockIdx.x * 256 + threadIdx.x;
    if (v < NROW) atomIdx[v] = s_is64 ? (int)atomw[2 * v] : (int)atomw[v];
}

// ---- prep: bit-pack adjacency + transpose in one pass ----
// Block = (e, 64-row tile). Ballot masks into LDS, then fully-coalesced kc-major writes:
// packedT[(e*KC + kc)*NPAD + r] (512 B contiguous runs).
__global__ __launch_bounds__(256) void prep_pack_kernel(const int* __restrict__ adjs,
                                                        unsigned long long* __restrict__ packedT) {
    __shared__ unsigned long long slds[64][KW + 1];   // 41.5 KB, pad breaks bank alias
    const int e = blockIdx.y;
    const int r0 = blockIdx.x * 64;
    const int wave = threadIdx.x >> 6;
    const int lane = threadIdx.x & 63;
    const int tid = threadIdx.x;

    for (int rl = 0; rl < 64; ++rl) {
        const int r = r0 + rl;
        const bool rok = (r < NROW);
        const int* rowp = adjs + ((size_t)e * NROW + (rok ? r : 0)) * NROW;
#pragma unroll 5
        for (int cc = 0; cc < KCQ; ++cc) {
            int c = wave * KCQ + cc;
            int u = c * 64 + lane;
            int val = (rok && u < NROW) ? rowp[u] : 0;
            unsigned long long m = __ballot(val == 1);
            if (lane == 0) slds[rl][c] = m;
        }
    }
    __syncthreads();
#pragma unroll
    for (int p = 0; p < 20; ++p) {       // 64 r x 80 kc = 5120 words / 256 thr
        int idx = p * 256 + tid;
        int kc = idx >> 6;
        int rr = idx & 63;
        packedT[((size_t)e * KC + kc) * NPAD + r0 + rr] = slds[rr][kc];
    }
}

// ------- prep: h0 -> fragment-major f16 digit planes from fp32 embedding -------
__global__ __launch_bounds__(256) void prep_h0T_kernel(const int* __restrict__ atomIdx,
                                                       const float* __restrict__ emb,
                                                       unsigned short* __restrict__ hTt) {
    const int i = blockIdx.y;
    const int v = blockIdx.x * 256 + threadIdx.x;   // < NPAD (k index)
    float val = 0.f;
    if (v < NROW) val = emb[(size_t)atomIdx[v] * HDIM + i];
    unsigned short d1, d0;
    fx_digits(val, d1, d0);
    const int kc = v >> 6, kk = (v >> 4) & 3, half = (v >> 3) & 1, j = v & 7;
    hTt[bt_idx(kc, 0, kk, half, i, j)] = d1;
    hTt[bt_idx(kc, 1, kk, half, i, j)] = d0;
}

// ---------------- prep: h0 fp32 row-major state ----------------
__global__ __launch_bounds__(256) void prep_h0f_kernel(const int* __restrict__ atomIdx,
                                                       const float* __restrict__ emb,
                                                       float* __restrict__ h) {
    int idx = blockIdx.x * 256 + threadIdx.x;   // < NROW*HDIM
    int v = idx >> 7, i = idx & 127;
    h[idx] = emb[(size_t)atomIdx[v] * HDIM + i];
}

// ---------------- prep: Htr[(e*128+j)*128 + i] = H[e][i][j] (fp32) ----------------
__global__ __launch_bounds__(256) void prep_Ht_kernel(const float* __restrict__ H,
                                                      float* __restrict__ Htr) {
    int idx = blockIdx.x * 256 + threadIdx.x;   // < 4*128*128
    int e = idx >> 14;
    int j = (idx >> 7) & 127;
    int i = idx & 127;
    Htr[idx] = H[((size_t)e * HDIM + i) * HDIM + j];
}

// ---- GEMM1 (EXACT, barrier-free, LDS-free, 32x32x16 MFMA): agg = A * h ----
// Block 256 thr = 4 waves; block tile 128r x 128c; wave tile 128r x 32c.
// Grid 40 x 4e x 4kz = 640 blocks @ 2 blocks/CU. acc = 128 AGPR (MTI=4, no spill).
// Explicit 2-deep register double-buffer on A-words + B-fragments hides load latency.
// A frag: row=lane&31, k=(lane>>5)*8+j. C/D: col=lane&31, row=(reg&3)+8*(reg>>2)+4*(lane>>5).
__global__ __launch_bounds__(256, 2) void gemm1_kernel(const unsigned long long* __restrict__ packedT,
                                                       const unsigned short* __restrict__ hTt,
                                                       float* __restrict__ agg) {
    const int m0 = blockIdx.x * MROWS;
    const int e = blockIdx.y;
    const int kz = blockIdx.z;
    const int tid = threadIdx.x;
    const int lane = tid & 63;
    const int wave = tid >> 6;
    const int l31 = lane & 31;
    const int l1 = lane >> 5;            // half-wave selector
    const int sh2 = l1 * 8;              // bit offset within 16-bit k-group
    const int col = wave * 32 + l31;
    const int kc0 = kz * KCQ;

    f32x16 acc[2][MTI];                  // [pl][mt] = 128 AGPR
#pragma unroll
    for (int pl = 0; pl < 2; ++pl)
#pragma unroll
        for (int mt = 0; mt < MTI; ++mt) acc[pl][mt] = (f32x16)(0.f);

    const unsigned long long* abase = packedT + ((size_t)e * KC + kc0) * NPAD + m0 + l31;
    const _Float16* bbase = (const _Float16*)hTt + (size_t)kc0 * 16384 +
                            (size_t)l1 * 1024 + (size_t)col * 8;

    unsigned long long aw0[MTI], aw1[MTI];
    f16x8 bf0[2][4], bf1[2][4];

#define LOADK(AW, BF, K)                                                          \
    {                                                                             \
        const unsigned long long* ap_ = abase + (size_t)(K) * NPAD;               \
        _Pragma("unroll") for (int mt = 0; mt < MTI; ++mt) AW[mt] = ap_[mt * 32]; \
        const _Float16* bp_ = bbase + (size_t)(K) * 16384;                        \
        _Pragma("unroll") for (int pl = 0; pl < 2; ++pl)                          \
            _Pragma("unroll") for (int kk = 0; kk < 4; ++kk)                      \
                BF[pl][kk] = *(const f16x8*)(bp_ + pl * 8192 + kk * 2048);        \
    }

#define COMPK(AW, BF)                                                             \
    {                                                                             \
        _Pragma("unroll") for (int kk = 0; kk < 4; ++kk) {                        \
            _Pragma("unroll") for (int mt = 0; mt < MTI; ++mt) {                  \
                unsigned int w = (kk < 2) ? (unsigned int)AW[mt]                  \
                                          : (unsigned int)(AW[mt] >> 32);         \
                unsigned int b = (w >> ((kk & 1) * 16 + sh2)) & 0xFFu;            \
                unsigned int y = b | (b << 15);                                   \
                union { unsigned int u[4]; f16x8 h; } Af;                         \
                _Pragma("unroll") for (int q = 0; q < 4; ++q)                     \
                    Af.u[q] = ((y >> (2 * q)) & 0x00010001u) * 0x3C00u;           \
                _Pragma("unroll") for (int pl = 0; pl < 2; ++pl)                  \
                    acc[pl][mt] = __builtin_amdgcn_mfma_f32_32x32x16_f16(         \
                        Af.h, BF[pl][kk], acc[pl][mt], 0, 0, 0);                  \
            }                                                                     \
        }                                                                         \
    }

    LOADK(aw0, bf0, 0)
    for (int kc2 = 0; kc2 < KCQ; kc2 += 2) {
        LOADK(aw1, bf1, kc2 + 1)
        COMPK(aw0, bf0)
        if (kc2 + 2 < KCQ) LOADK(aw0, bf0, kc2 + 2)
        COMPK(aw1, bf1)
    }
#undef LOADK
#undef COMPK

    // epilogue: exact digit combine in double, one optimal fp32 rounding
    float* aggz = agg + (size_t)kz * PART;
#pragma unroll
    for (int mt = 0; mt < MTI; ++mt)
#pragma unroll
        for (int reg = 0; reg < 16; ++reg) {
            int row = (reg & 3) + 8 * (reg >> 2) + 4 * l1;
            int v = m0 + mt * 32 + row;
            if (v < NROW) {
                double d = (double)acc[0][mt][reg] * 2048.0 + (double)acc[1][mt][reg];
                aggz[((size_t)e * NROW + v) * HDIM + col] = (float)(d * (1.0 / 4194304.0));
            }
        }
}

// --- GEMM2: msg[v][i] = sum_ej Htr[ej][i]*agg[v][ej], sigmoid, fp32 out + digits ---
// 8-row tiles, 625 blocks (5000 rows exactly), 2x2 register blocking, float2 I/O.
__global__ __launch_bounds__(256) void gemm2_kernel(const float* __restrict__ agg,
                                                    const float* __restrict__ Htr,
                                                    float* __restrict__ hf,       // fp32 state, in/out
                                                    float* __restrict__ outp,     // d_out slice t (fp32)
                                                    unsigned short* __restrict__ hTt) {
    __shared__ float aggs[8][512];             // 16 KB
    __shared__ unsigned short hs[2][128][8];   // 4 KB digit transpose buffers
    const int tid = threadIdx.x;
    const int v0 = blockIdx.x * 8;             // < 5000 always (625*8 = 5000)

    // stage 8 rows x 512 (sum of 4 kz parts), float4
#pragma unroll
    for (int it = 0; it < 4; ++it) {
        int idx = it * 256 + tid;          // float4 index, 0..1023
        int r = idx >> 7;
        int c = (idx & 127) * 4;
        int e = c >> 7, j = c & 127;
        size_t o = ((size_t)e * NROW + (v0 + r)) * HDIM + j;
        float4 a0 = *(const float4*)&agg[o];
        float4 a1 = *(const float4*)&agg[PART + o];
        float4 a2 = *(const float4*)&agg[2 * PART + o];
        float4 a3 = *(const float4*)&agg[3 * PART + o];
        *(float4*)&aggs[r][c] = make_float4((a0.x + a1.x) + (a2.x + a3.x),
                                            (a0.y + a1.y) + (a2.y + a3.y),
                                            (a0.z + a1.z) + (a2.z + a3.z),
                                            (a0.w + a1.w) + (a2.w + a3.w));
    }
    __syncthreads();

    const int ip = tid & 63;
    const int vg = tid >> 6;             // 0..3 -> rows vg*2, vg*2+1
    const int i0 = ip * 2;

    float m[2][2][4];                    // [row][i-col][k-lane]
#pragma unroll
    for (int r = 0; r < 2; ++r)
#pragma unroll
        for (int q = 0; q < 2; ++q)
#pragma unroll
            for (int k = 0; k < 4; ++k) m[r][q][k] = 0.f;

    const int rb = vg * 2;
    for (int cg = 0; cg < 128; ++cg) {
        int c = cg * 4;
        float4 q0 = *(const float4*)&aggs[rb][c];       // broadcast, conflict-free
        float4 q1 = *(const float4*)&aggs[rb + 1][c];
        float a0v[4] = {q0.x, q0.y, q0.z, q0.w};
        float a1v[4] = {q1.x, q1.y, q1.z, q1.w};
#pragma unroll
        for (int k = 0; k < 4; ++k) {
            float2 w = *(const float2*)&Htr[(size_t)(c + k) * HDIM + i0];
            m[0][0][k] += a0v[k] * w.x;
            m[0][1][k] += a0v[k] * w.y;
            m[1][0][k] += a1v[k] * w.x;
            m[1][1][k] += a1v[k] * w.y;
        }
    }

#pragma unroll
    for (int r = 0; r < 2; ++r) {
        int vr = rb + r;
        int v = v0 + vr;
        size_t o = (size_t)v * HDIM + i0;
        float2 hv = *(const float2*)&hf[o];
        float ms0 = (m[r][0][0] + m[r][0][1]) + (m[r][0][2] + m[r][0][3]);
        float ms1 = (m[r][1][0] + m[r][1][1]) + (m[r][1][2] + m[r][1][3]);
        float x0 = hv.x + ms0;
        float x1 = hv.y + ms1;
        float s0 = 1.0f / (1.0f + expf(-x0));
        float s1 = 1.0f / (1.0f + expf(-x1));
        *(float2*)&outp[o] = make_float2(s0, s1);
        *(float2*)&hf[o] = make_float2(s0, s1);
        unsigned short d1a, d0a, d1b, d0b;
        fx_digits(s0, d1a, d0a);
        fx_digits(s1, d1b, d0b);
        hs[0][i0][vr] = d1a;
        hs[1][i0][vr] = d0a;
        hs[0][i0 + 1][vr] = d1b;
        hs[1][i0 + 1][vr] = d0b;
    }
    __syncthreads();
    if (tid < 128) {    // one uint4 (8 k-entries) per plane, coalesced
        const int kc = v0 >> 6, kk = (v0 >> 4) & 3, half = (v0 >> 3) & 1;
#pragma unroll
        for (int pl = 0; pl < 2; ++pl)
            *(uint4*)&hTt[bt_idx(kc, pl, kk, half, tid, 0)] = *(const uint4*)&hs[pl][tid][0];
    }
}

extern "C" void kernel_launch(void* const* d_in, const int* in_sizes, int n_in,
                              void* d_out, int out_size, void* d_ws, size_t ws_size,
                              hipStream_t stream) {
    const unsigned int* atomw = (const unsigned int*)d_in[0];  // int32 OR int64 — sniffed on device
    const int* adjs = (const int*)d_in[1];                     // int32
    // d_in[2] = max_time_steps; reference constant T=4 hard-coded
    const float* emb = (const float*)d_in[3];                  // fp32
    const float* H = (const float*)d_in[4];                    // fp32
    float* out = (float*)d_out;                                // fp32 output

    char* ws = (char*)d_ws;
    unsigned long long* packedT = (unsigned long long*)ws;           // 13,107,200 B (kc-major)
    size_t off = (size_t)4 * KC * NPAD * 8;
    unsigned short* hTt = (unsigned short*)(ws + off);               // 2 planes fragment-major
    off += (size_t)2 * KC * HDIM * 64 * 2;
    float* hf = (float*)(ws + off);                                  // 2,560,000 B
    off += (size_t)NROW * HDIM * 4;
    float* agg = (float*)(ws + off);                                 // 4 parts = 40,960,000 B
    off += (size_t)KZ * PART * 4;
    float* Htr = (float*)(ws + off);                                 // 262,144 B
    off += (size_t)4 * HDIM * HDIM * 4;
    int* atomIdx = (int*)(ws + off);                                 // 20,000 B
    off += (size_t)NROW * 4;

    prep_atom_kernel<<<dim3((NROW + 255) / 256), 256, 0, stream>>>(atomw, atomIdx);
    prep_pack_kernel<<<dim3(NPAD / 64, 4), 256, 0, stream>>>(adjs, packedT);
    prep_h0T_kernel<<<dim3(NPAD / 256, HDIM), 256, 0, stream>>>(atomIdx, emb, hTt);
    prep_h0f_kernel<<<dim3(NROW * HDIM / 256), 256, 0, stream>>>(atomIdx, emb, hf);
    prep_Ht_kernel<<<dim3(4 * HDIM * HDIM / 256), 256, 0, stream>>>(H, Htr);

    for (int t = 0; t < 4; ++t) {
        gemm1_kernel<<<dim3(NPAD / MROWS, 4, KZ), 256, 0, stream>>>(packedT, hTt, agg);
        gemm2_kernel<<<dim3(NROW / 8), 256, 0, stream>>>(agg, Htr, hf,
                                                         out + (size_t)t * NROW * HDIM, hTt);
    }
}

// Round 4
// 1004.789 us; speedup vs baseline: 2.3293x; 1.4968x over previous
//
#include <hip/hip_runtime.h>

#define NROW 5000
#define NPAD 5120   // padded rows
#define KW   80     // u64 words per padded row
#define KC   80     // 64-k chunks
#define KZ   4      // split-K
#define KCQ  20     // chunks per split
#define HDIM 128
#define MTI  4      // 32-row MFMA tiles per block (128 rows); acc = 128 AGPR, no spill
#define MROWS (MTI * 32)
#define FXS  4194304.0f                  // 2^22 fixed-point scale
#define PART ((size_t)4 * NROW * HDIM)   // agg elements per kz part

typedef _Float16 f16x8 __attribute__((ext_vector_type(8)));
typedef float f32x16 __attribute__((ext_vector_type(16)));

__device__ __forceinline__ unsigned short f2h_int(int v) {   // exact for |v| <= 2048
    union { _Float16 h; unsigned short u; } c;
    c.h = (_Float16)(float)v;
    return c.u;
}
// q = round(h*2^22); digits base 2048: q == d1*2048 + d0
__device__ __forceinline__ void fx_digits(float h, unsigned short& d1, unsigned short& d0) {
    int q = (int)rintf(h * FXS);
    d1 = f2h_int(q >> 11);
    d0 = f2h_int(q & 2047);
}

// Fragment-major B layout: element (kc, pl, kk, half, col, j) holds digit plane pl of
// k = kc*64 + kk*16 + half*8 + j for column col. A wave's f16x8 fragment load is
// contiguous (512 B per half-wave). strides in f16 units: kc 16384, pl 8192, kk 2048,
// half 1024, col 8.
__device__ __forceinline__ size_t bt_idx(int kc, int pl, int kk, int half, int col, int j) {
    return (((((size_t)kc * 2 + pl) * 4 + kk) * 2 + half) * 128 + col) * 8 + j;
}

// ---- prep: resolve atom indices; detect int32 vs int64 storage device-side ----
__global__ __launch_bounds__(256) void prep_atom_kernel(const unsigned int* __restrict__ atomw,
                                                        int* __restrict__ atomIdx) {
    __shared__ int s_is64;
    if (threadIdx.x == 0) {
        bool all0 = true, anynz = false;
        for (int j = 0; j < 64; ++j) {
            unsigned lo = atomw[2 * j], hi = atomw[2 * j + 1];
            all0 = all0 && (hi == 0u);
            anynz = anynz || (lo != 0u);
        }
        s_is64 = (all0 && anynz) ? 1 : 0;
    }
    __syncthreads();
    int v = blockIdx.x * 256 + threadIdx.x;
    if (v < NROW) atomIdx[v] = s_is64 ? (int)atomw[2 * v] : (int)atomw[v];
}

// ---- prep: bit-pack adjacency, ROW-major (one block per (e,row) = 20480 blocks, max MLP) ----
__global__ __launch_bounds__(256) void prep_pack_kernel(const int* __restrict__ adjs,
                                                        unsigned long long* __restrict__ packedR) {
    const int er = blockIdx.x;            // [0, 4*NPAD)
    const int e = er / NPAD;
    const int r = er - e * NPAD;
    const int wave = threadIdx.x >> 6;
    const int lane = threadIdx.x & 63;
    const int* rowp = adjs + ((size_t)e * NROW + r) * NROW;
    unsigned long long* outp = packedR + ((size_t)e * NPAD + r) * KW;
    const bool rok = (r < NROW);
    for (int c = wave; c < KW; c += 4) {
        int u = c * 64 + lane;
        int val = (rok && u < NROW) ? rowp[u] : 0;
        unsigned long long m = __ballot(val == 1);
        if (lane == 0) outp[c] = m;
    }
}

// ---- prep: transpose packed bits row-major -> kc-major via LDS (coalesced both sides) ----
// Block = (64-row tile, e); reads 64x80 u64 coalesced along c, writes 512 B runs along r.
__global__ __launch_bounds__(256) void prep_packT_kernel(const unsigned long long* __restrict__ packedR,
                                                         unsigned long long* __restrict__ packedT) {
    __shared__ unsigned long long slds[64][KW + 1];   // 41.5 KB, pad breaks bank alias
    const int e = blockIdx.y;
    const int r0 = blockIdx.x * 64;
    const int tid = threadIdx.x;
#pragma unroll
    for (int p = 0; p < 20; ++p) {        // 64 r x 80 c = 5120 words / 256 thr
        int idx = p * 256 + tid;
        int r = idx / KW;
        int c = idx - r * KW;
        slds[r][c] = packedR[((size_t)e * NPAD + r0 + r) * KW + c];
    }
    __syncthreads();
#pragma unroll
    for (int p = 0; p < 20; ++p) {
        int idx = p * 256 + tid;
        int kc = idx >> 6;
        int rr = idx & 63;
        packedT[((size_t)e * KC + kc) * NPAD + r0 + rr] = slds[rr][kc];
    }
}

// ------- prep: h0 -> fragment-major f16 digit planes from fp32 embedding -------
__global__ __launch_bounds__(256) void prep_h0T_kernel(const int* __restrict__ atomIdx,
                                                       const float* __restrict__ emb,
                                                       unsigned short* __restrict__ hTt) {
    const int i = blockIdx.y;
    const int v = blockIdx.x * 256 + threadIdx.x;   // < NPAD (k index)
    float val = 0.f;
    if (v < NROW) val = emb[(size_t)atomIdx[v] * HDIM + i];
    unsigned short d1, d0;
    fx_digits(val, d1, d0);
    const int kc = v >> 6, kk = (v >> 4) & 3, half = (v >> 3) & 1, j = v & 7;
    hTt[bt_idx(kc, 0, kk, half, i, j)] = d1;
    hTt[bt_idx(kc, 1, kk, half, i, j)] = d0;
}

// ---------------- prep: h0 fp32 row-major state ----------------
__global__ __launch_bounds__(256) void prep_h0f_kernel(const int* __restrict__ atomIdx,
                                                       const float* __restrict__ emb,
                                                       float* __restrict__ h) {
    int idx = blockIdx.x * 256 + threadIdx.x;   // < NROW*HDIM
    int v = idx >> 7, i = idx & 127;
    h[idx] = emb[(size_t)atomIdx[v] * HDIM + i];
}

// ---------------- prep: Htr[(e*128+j)*128 + i] = H[e][i][j] (fp32) ----------------
__global__ __launch_bounds__(256) void prep_Ht_kernel(const float* __restrict__ H,
                                                      float* __restrict__ Htr) {
    int idx = blockIdx.x * 256 + threadIdx.x;   // < 4*128*128
    int e = idx >> 14;
    int j = (idx >> 7) & 127;
    int i = idx & 127;
    Htr[idx] = H[((size_t)e * HDIM + i) * HDIM + j];
}

// ---- GEMM1 (EXACT, barrier-free, LDS-free, 32x32x16 MFMA): agg = A * h ----
// Block 256 thr = 4 waves; block tile 128r x 128c; wave tile 128r x 32c.
// Grid 40 x 4e x 4kz = 640 blocks @ 2 blocks/CU. acc = 128 AGPR (MTI=4, no spill).
// Explicit 2-deep register double-buffer on A-words + B-fragments hides load latency.
// A frag: row=lane&31, k=(lane>>5)*8+j. C/D: col=lane&31, row=(reg&3)+8*(reg>>2)+4*(lane>>5).
__global__ __launch_bounds__(256, 2) void gemm1_kernel(const unsigned long long* __restrict__ packedT,
                                                       const unsigned short* __restrict__ hTt,
                                                       float* __restrict__ agg) {
    const int m0 = blockIdx.x * MROWS;
    const int e = blockIdx.y;
    const int kz = blockIdx.z;
    const int tid = threadIdx.x;
    const int lane = tid & 63;
    const int wave = tid >> 6;
    const int l31 = lane & 31;
    const int l1 = lane >> 5;            // half-wave selector
    const int sh2 = l1 * 8;              // bit offset within 16-bit k-group
    const int col = wave * 32 + l31;
    const int kc0 = kz * KCQ;

    f32x16 acc[2][MTI];                  // [pl][mt] = 128 AGPR
#pragma unroll
    for (int pl = 0; pl < 2; ++pl)
#pragma unroll
        for (int mt = 0; mt < MTI; ++mt) acc[pl][mt] = (f32x16)(0.f);

    const unsigned long long* abase = packedT + ((size_t)e * KC + kc0) * NPAD + m0 + l31;
    const _Float16* bbase = (const _Float16*)hTt + (size_t)kc0 * 16384 +
                            (size_t)l1 * 1024 + (size_t)col * 8;

    unsigned long long aw0[MTI], aw1[MTI];
    f16x8 bf0[2][4], bf1[2][4];

#define LOADK(AW, BF, K)                                                          \
    {                                                                             \
        const unsigned long long* ap_ = abase + (size_t)(K) * NPAD;               \
        _Pragma("unroll") for (int mt = 0; mt < MTI; ++mt) AW[mt] = ap_[mt * 32]; \
        const _Float16* bp_ = bbase + (size_t)(K) * 16384;                        \
        _Pragma("unroll") for (int pl = 0; pl < 2; ++pl)                          \
            _Pragma("unroll") for (int kk = 0; kk < 4; ++kk)                      \
                BF[pl][kk] = *(const f16x8*)(bp_ + pl * 8192 + kk * 2048);        \
    }

#define COMPK(AW, BF)                                                             \
    {                                                                             \
        _Pragma("unroll") for (int kk = 0; kk < 4; ++kk) {                        \
            _Pragma("unroll") for (int mt = 0; mt < MTI; ++mt) {                  \
                unsigned int w = (kk < 2) ? (unsigned int)AW[mt]                  \
                                          : (unsigned int)(AW[mt] >> 32);         \
                unsigned int b = (w >> ((kk & 1) * 16 + sh2)) & 0xFFu;            \
                unsigned int y = b | (b << 15);                                   \
                union { unsigned int u[4]; f16x8 h; } Af;                         \
                _Pragma("unroll") for (int q = 0; q < 4; ++q)                     \
                    Af.u[q] = ((y >> (2 * q)) & 0x00010001u) * 0x3C00u;           \
                _Pragma("unroll") for (int pl = 0; pl < 2; ++pl)                  \
                    acc[pl][mt] = __builtin_amdgcn_mfma_f32_32x32x16_f16(         \
                        Af.h, BF[pl][kk], acc[pl][mt], 0, 0, 0);                  \
            }                                                                     \
        }                                                                         \
    }

    LOADK(aw0, bf0, 0)
    for (int kc2 = 0; kc2 < KCQ; kc2 += 2) {
        LOADK(aw1, bf1, kc2 + 1)
        COMPK(aw0, bf0)
        if (kc2 + 2 < KCQ) LOADK(aw0, bf0, kc2 + 2)
        COMPK(aw1, bf1)
    }
#undef LOADK
#undef COMPK

    // epilogue: exact digit combine in double, one optimal fp32 rounding
    float* aggz = agg + (size_t)kz * PART;
#pragma unroll
    for (int mt = 0; mt < MTI; ++mt)
#pragma unroll
        for (int reg = 0; reg < 16; ++reg) {
            int row = (reg & 3) + 8 * (reg >> 2) + 4 * l1;
            int v = m0 + mt * 32 + row;
            if (v < NROW) {
                double d = (double)acc[0][mt][reg] * 2048.0 + (double)acc[1][mt][reg];
                aggz[((size_t)e * NROW + v) * HDIM + col] = (float)(d * (1.0 / 4194304.0));
            }
        }
}

// --- GEMM2: msg[v][i] = sum_ej Htr[ej][i]*agg[v][ej], sigmoid, fp32 out + digits ---
// 8-row tiles, 625 blocks (5000 rows exactly), 2x2 register blocking, float2 I/O.
__global__ __launch_bounds__(256) void gemm2_kernel(const float* __restrict__ agg,
                                                    const float* __restrict__ Htr,
                                                    float* __restrict__ hf,       // fp32 state, in/out
                                                    float* __restrict__ outp,     // d_out slice t (fp32)
                                                    unsigned short* __restrict__ hTt) {
    __shared__ float aggs[8][512];             // 16 KB
    __shared__ unsigned short hs[2][128][8];   // 4 KB digit transpose buffers
    const int tid = threadIdx.x;
    const int v0 = blockIdx.x * 8;             // < 5000 always (625*8 = 5000)

    // stage 8 rows x 512 (sum of 4 kz parts), float4
#pragma unroll
    for (int it = 0; it < 4; ++it) {
        int idx = it * 256 + tid;          // float4 index, 0..1023
        int r = idx >> 7;
        int c = (idx & 127) * 4;
        int e = c >> 7, j = c & 127;
        size_t o = ((size_t)e * NROW + (v0 + r)) * HDIM + j;
        float4 a0 = *(const float4*)&agg[o];
        float4 a1 = *(const float4*)&agg[PART + o];
        float4 a2 = *(const float4*)&agg[2 * PART + o];
        float4 a3 = *(const float4*)&agg[3 * PART + o];
        *(float4*)&aggs[r][c] = make_float4((a0.x + a1.x) + (a2.x + a3.x),
                                            (a0.y + a1.y) + (a2.y + a3.y),
                                            (a0.z + a1.z) + (a2.z + a3.z),
                                            (a0.w + a1.w) + (a2.w + a3.w));
    }
    __syncthreads();

    const int ip = tid & 63;
    const int vg = tid >> 6;             // 0..3 -> rows vg*2, vg*2+1
    const int i0 = ip * 2;

    float m[2][2][4];                    // [row][i-col][k-lane]
#pragma unroll
    for (int r = 0; r < 2; ++r)
#pragma unroll
        for (int q = 0; q < 2; ++q)
#pragma unroll
            for (int k = 0; k < 4; ++k) m[r][q][k] = 0.f;

    const int rb = vg * 2;
    for (int cg = 0; cg < 128; ++cg) {
        int c = cg * 4;
        float4 q0 = *(const float4*)&aggs[rb][c];       // broadcast, conflict-free
        float4 q1 = *(const float4*)&aggs[rb + 1][c];
        float a0v[4] = {q0.x, q0.y, q0.z, q0.w};
        float a1v[4] = {q1.x, q1.y, q1.z, q1.w};
#pragma unroll
        for (int k = 0; k < 4; ++k) {
            float2 w = *(const float2*)&Htr[(size_t)(c + k) * HDIM + i0];
            m[0][0][k] += a0v[k] * w.x;
            m[0][1][k] += a0v[k] * w.y;
            m[1][0][k] += a1v[k] * w.x;
            m[1][1][k] += a1v[k] * w.y;
        }
    }

#pragma unroll
    for (int r = 0; r < 2; ++r) {
        int vr = rb + r;
        int v = v0 + vr;
        size_t o = (size_t)v * HDIM + i0;
        float2 hv = *(const float2*)&hf[o];
        float ms0 = (m[r][0][0] + m[r][0][1]) + (m[r][0][2] + m[r][0][3]);
        float ms1 = (m[r][1][0] + m[r][1][1]) + (m[r][1][2] + m[r][1][3]);
        float x0 = hv.x + ms0;
        float x1 = hv.y + ms1;
        float s0 = 1.0f / (1.0f + expf(-x0));
        float s1 = 1.0f / (1.0f + expf(-x1));
        *(float2*)&outp[o] = make_float2(s0, s1);
        *(float2*)&hf[o] = make_float2(s0, s1);
        unsigned short d1a, d0a, d1b, d0b;
        fx_digits(s0, d1a, d0a);
        fx_digits(s1, d1b, d0b);
        hs[0][i0][vr] = d1a;
        hs[1][i0][vr] = d0a;
        hs[0][i0 + 1][vr] = d1b;
        hs[1][i0 + 1][vr] = d0b;
    }
    __syncthreads();
    if (tid < 128) {    // one uint4 (8 k-entries) per plane, coalesced
        const int kc = v0 >> 6, kk = (v0 >> 4) & 3, half = (v0 >> 3) & 1;
#pragma unroll
        for (int pl = 0; pl < 2; ++pl)
            *(uint4*)&hTt[bt_idx(kc, pl, kk, half, tid, 0)] = *(const uint4*)&hs[pl][tid][0];
    }
}

extern "C" void kernel_launch(void* const* d_in, const int* in_sizes, int n_in,
                              void* d_out, int out_size, void* d_ws, size_t ws_size,
                              hipStream_t stream) {
    const unsigned int* atomw = (const unsigned int*)d_in[0];  // int32 OR int64 — sniffed on device
    const int* adjs = (const int*)d_in[1];                     // int32
    // d_in[2] = max_time_steps; reference constant T=4 hard-coded
    const float* emb = (const float*)d_in[3];                  // fp32
    const float* H = (const float*)d_in[4];                    // fp32
    float* out = (float*)d_out;                                // fp32 output

    char* ws = (char*)d_ws;
    unsigned long long* packedT = (unsigned long long*)ws;           // 13,107,200 B (kc-major)
    size_t off = (size_t)4 * KC * NPAD * 8;
    unsigned short* hTt = (unsigned short*)(ws + off);               // 2 planes fragment-major
    off += (size_t)2 * KC * HDIM * 64 * 2;
    float* hf = (float*)(ws + off);                                  // 2,560,000 B
    off += (size_t)NROW * HDIM * 4;
    float* agg = (float*)(ws + off);                                 // 4 parts = 40,960,000 B
    off += (size_t)KZ * PART * 4;
    float* Htr = (float*)(ws + off);                                 // 262,144 B
    off += (size_t)4 * HDIM * HDIM * 4;
    int* atomIdx = (int*)(ws + off);                                 // 20,000 B
    off += (size_t)NROW * 4;
    off = (off + 255) & ~(size_t)255;
    unsigned long long* packedR = (unsigned long long*)(ws + off);   // 13,107,200 B (row-major)
    off += (size_t)4 * NPAD * KW * 8;

    prep_atom_kernel<<<dim3((NROW + 255) / 256), 256, 0, stream>>>(atomw, atomIdx);
    prep_pack_kernel<<<dim3(4 * NPAD), 256, 0, stream>>>(adjs, packedR);
    prep_packT_kernel<<<dim3(NPAD / 64, 4), 256, 0, stream>>>(packedR, packedT);
    prep_h0T_kernel<<<dim3(NPAD / 256, HDIM), 256, 0, stream>>>(atomIdx, emb, hTt);
    prep_h0f_kernel<<<dim3(NROW * HDIM / 256), 256, 0, stream>>>(atomIdx, emb, hf);
    prep_Ht_kernel<<<dim3(4 * HDIM * HDIM / 256), 256, 0, stream>>>(H, Htr);

    for (int t = 0; t < 4; ++t) {
        gemm1_kernel<<<dim3(NPAD / MROWS, 4, KZ), 256, 0, stream>>>(packedT, hTt, agg);
        gemm2_kernel<<<dim3(NROW / 8), 256, 0, stream>>>(agg, Htr, hf,
                                                         out + (size_t)t * NROW * HDIM, hTt);
    }
}